// Round 2
// baseline (15978.175 us; speedup 1.0000x reference)
//
#include <hip/hip_runtime.h>
#include <cmath>

#define BN 2048
#define DXC 256
#define DZC 64
#define INV_B (1.0f/2048.0f)
#define NITER 50
#define US 264   // U row stride (cols 0..255 = X^T T, 256 = col-sums of T, 257 = sqx-weighted col-sums)
#define VS 68    // V / z' row stride (cols 0..63 = M1@Z, 64 = M1@1, 65 = M1@sqz)
#define NSPK1 4
#define NSPK3 8
#define NSPC 32

// ---- workspace layout (float offsets) ----
#define OFF_K    ((size_t)0)
#define OFF_M1   (OFF_K + (size_t)BN*BN)
#define OFF_U    (OFF_M1 + (size_t)BN*BN)
#define OFF_UP   (OFF_U + (size_t)BN*US)
#define OFF_V    (OFF_UP + (size_t)NSPK1*BN*US)
#define OFF_VP   (OFF_V + (size_t)BN*VS)
#define OFF_ZP   (OFF_VP + (size_t)NSPK3*BN*VS)
#define OFF_SQX  (OFF_ZP + (size_t)BN*VS)
#define OFF_SQZ  (OFF_SQX + BN)
#define OFF_CX   (OFF_SQZ + BN)
#define OFF_CZ   (OFF_CX + BN)
#define OFF_R    (OFF_CZ + BN)
#define OFF_C    (OFF_R + BN)
#define OFF_RSQX (OFF_C + BN)
#define OFF_RSQZ (OFF_RSQX + BN)
#define OFF_CP1  (OFF_RSQZ + BN)
#define OFF_CP2  (OFF_CP1 + (size_t)NSPC*BN)
#define OFF_SCAL (OFF_CP2 + (size_t)NSPC*BN)
#define OFF_RMX  (OFF_SCAL + 64)     // BN sortable-uint row maxima of expo
// scal: 0=sum Craw_x, 1=sum Craw_z, 2=sx, 3=sz, 4=sum constx, 5=sum constz,
//       6=cross_term, 7=reg_sum, 8=sum sqx

__device__ __forceinline__ void fma16(float (&acc)[4][4], const float* a4, const float* b4){
  #pragma unroll
  for (int m=0;m<4;m++)
    #pragma unroll
    for (int n=0;n<4;n++)
      acc[m][n] = fmaf(a4[m], b4[n], acc[m][n]);
}

__device__ __forceinline__ float wave_sum(float v){
  for (int o=32;o;o>>=1) v += __shfl_down(v,o);
  return v;
}

// sortable-uint encoding for float atomicMax over signed values
__device__ __forceinline__ unsigned encf(float f){
  unsigned u = __float_as_uint(f);
  return (u & 0x80000000u) ? ~u : (u | 0x80000000u);
}
__device__ __forceinline__ float decf(unsigned u){
  return (u & 0x80000000u) ? __uint_as_float(u & 0x7fffffffu) : __uint_as_float(~u);
}

// ---------------- setup kernels ----------------

__global__ __launch_bounds__(256) void k_zero(float* __restrict__ ws){
  int t = blockIdx.x*256 + threadIdx.x;
  if (t < BN) { ws[OFF_RSQX + t] = 0.f; ws[OFF_RSQZ + t] = 0.f; }
  if (t < 64) ws[OFF_SCAL + t] = 0.f;
}

__global__ __launch_bounds__(64) void k_sq_x(const float* __restrict__ x, float* __restrict__ ws){
  int row = blockIdx.x, t = threadIdx.x;
  const float* xr = x + (size_t)row*DXC;
  float s = 0.f;
  for (int k = t; k < DXC; k += 64) { float v = xr[k]; s += v*v; }
  s = wave_sum(s);
  if (t == 0) { ws[OFF_SQX + row] = s; atomicAdd(&ws[OFF_SCAL+8], s); }
}

__global__ __launch_bounds__(64) void k_sq_z(const float* __restrict__ z, float* __restrict__ ws){
  int row = blockIdx.x, t = threadIdx.x;
  float v = (t < DZC) ? z[(size_t)row*DZC + t] : 0.f;
  float s = wave_sum(v*v);
  if (t == 0) ws[OFF_SQZ + row] = s;
}

// stats: sum of clipped Craw (-> scal[sumidx]) and per-row sum of Craw^2 (-> rowsq)
template<int D>
__global__ __launch_bounds__(64) void k_stats(const float* __restrict__ P,
                                              const float* __restrict__ sq,
                                              float* __restrict__ ws, int sumidx,
                                              float* __restrict__ rowsq){
  __shared__ __align__(16) float As[32][36];
  __shared__ __align__(16) float Bs[32][36];
  const int i0 = blockIdx.x*32, j0 = blockIdx.y*32;
  const int t = threadIdx.x, tr = t&7, tc = t>>3;
  float acc[4][4] = {};
  for (int k0 = 0; k0 < D; k0 += 32) {
    for (int l = t; l < 1024; l += 64) {
      const int rr = l>>5, cc = l&31;
      As[cc][rr] = P[(size_t)(i0+rr)*D + (k0+cc)];
      Bs[cc][rr] = P[(size_t)(j0+rr)*D + (k0+cc)];
    }
    __syncthreads();
    #pragma unroll
    for (int kk = 0; kk < 32; kk++) {
      float a[4], b[4];
      *(float4*)a = *(const float4*)&As[kk][tr*4];
      *(float4*)b = *(const float4*)&Bs[kk][tc*4];
      fma16(acc, a, b);
    }
    __syncthreads();
  }
  float sqi[4], sqj[4];
  #pragma unroll
  for (int m=0;m<4;m++) sqi[m] = sq[i0+tr*4+m];
  #pragma unroll
  for (int n=0;n<4;n++) sqj[n] = sq[j0+tc*4+n];
  float tot = 0.f; float rs[4] = {0.f,0.f,0.f,0.f};
  #pragma unroll
  for (int m=0;m<4;m++)
    #pragma unroll
    for (int n=0;n<4;n++) {
      float raw = sqi[m] + sqj[n] - 2.f*acc[m][n];
      float cr = fmaxf(raw, 0.f);
      tot += cr;
      rs[m] += cr*cr;
    }
  float v = wave_sum(tot);
  if (t==0) atomicAdd(&ws[OFF_SCAL+sumidx], v);
  #pragma unroll
  for (int m=0;m<4;m++){
    float x2 = rs[m];
    x2 += __shfl_down(x2,32); x2 += __shfl_down(x2,16); x2 += __shfl_down(x2,8);
    if (tc==0) atomicAdd(&rowsq[i0+tr*4+m], x2);
  }
}

__global__ __launch_bounds__(256) void k_s3(const float* __restrict__ z, float* __restrict__ ws){
  int j = blockIdx.x*256 + threadIdx.x;
  float mx = ws[OFF_SCAL+0] / ((float)BN*(float)BN);
  float sx = 1.f/(mx + 1e-8f);
  float mz = ws[OFF_SCAL+1] / ((float)BN*(float)BN);
  float sz = 1.f/(mz + 1e-8f);
  if (j == 0) { ws[OFF_SCAL+2] = sx; ws[OFF_SCAL+3] = sz; }
  if (j < BN) {
    float cx = ws[OFF_RSQX+j]*sx*sx*INV_B;
    float cz = ws[OFF_RSQZ+j]*sz*sz*INV_B;
    ws[OFF_CX+j] = cx; ws[OFF_CZ+j] = cz;
    atomicAdd(&ws[OFF_SCAL+4], cx);
    atomicAdd(&ws[OFF_SCAL+5], cz);
    ws[OFF_R+j] = 1.f; ws[OFF_C+j] = 1.f;
    float* zp = ws + OFF_ZP + (size_t)j*VS;
    for (int m=0;m<DZC;m++) zp[m] = z[(size_t)j*DZC + m];
    zp[DZC]   = 1.f;
    zp[DZC+1] = ws[OFF_SQZ+j];
    float msx = ws[OFF_SCAL+8]*INV_B;
    ws[OFF_U + (size_t)j*US + 256] = 1.f;    // sum_i T0[i,j]
    ws[OFF_U + (size_t)j*US + 257] = msx;    // sum_i sqx_i T0[i,j]
  }
}

__global__ __launch_bounds__(256) void k_initK(float* __restrict__ ws){
  size_t idx = ((size_t)blockIdx.x*256 + threadIdx.x)*4;
  float4 v = {INV_B, INV_B, INV_B, INV_B};
  *(float4*)(ws + OFF_K + idx) = v;
}

// ---------------- Sinkhorn iteration kernels ----------------

// k1: Upart[s][j][k] = sum_{i in split} (r_i x[i,k]) K[i,j] * c_j  (k<256)
__global__ __launch_bounds__(64) void k1_gemm(const float* __restrict__ x, float* __restrict__ ws){
  __shared__ __align__(16) float As[32][36];
  __shared__ __align__(16) float Bs[32][36];
  const int k0 = blockIdx.x*32, j0 = blockIdx.y*32;
  const int p0 = blockIdx.z*(BN/NSPK1);
  const int t = threadIdx.x, tr = t&7, tc = t>>3;
  const float* __restrict__ Kp = ws + OFF_K;
  const float* __restrict__ rv = ws + OFF_R;
  float acc[4][4] = {};
  for (int pc = 0; pc < BN/NSPK1; pc += 32) {
    const int pb = p0 + pc;
    for (int l = t; l < 1024; l += 64) {
      const int rr = l>>5, cc = l&31;
      As[rr][cc] = x[(size_t)(pb+rr)*DXC + (k0+cc)] * rv[pb+rr];
      Bs[rr][cc] = Kp[(size_t)(pb+rr)*BN + (j0+cc)];
    }
    __syncthreads();
    #pragma unroll
    for (int kk=0; kk<32; kk++){
      float a[4], b[4];
      *(float4*)a = *(const float4*)&As[kk][tr*4];
      *(float4*)b = *(const float4*)&Bs[kk][tc*4];
      fma16(acc, a, b);
    }
    __syncthreads();
  }
  float* __restrict__ Up = ws + OFF_UP + (size_t)blockIdx.z*BN*US;
  const float* __restrict__ cv = ws + OFF_C;
  #pragma unroll
  for (int n=0;n<4;n++){
    const int j = j0 + tc*4 + n;
    const float cj = cv[j];
    #pragma unroll
    for (int m=0;m<4;m++)
      Up[(size_t)j*US + (k0+tr*4+m)] = acc[m][n]*cj;
  }
}

__global__ __launch_bounds__(256) void k1_reduce(float* __restrict__ ws){
  int idx = blockIdx.x*256 + threadIdx.x;       // over BN*256
  int j = idx >> 8, k = idx & 255;
  size_t o = (size_t)j*US + k;
  float s = 0.f;
  #pragma unroll
  for (int sp=0; sp<NSPK1; sp++) s += ws[OFF_UP + (size_t)sp*BN*US + o];
  ws[OFF_U + o] = s;
}

// k2: M1[i,j] = sx*(sqx_i*U[j,256] + U[j,257] - 2*sum_k x[i,k]*U[j,k])
__global__ __launch_bounds__(64) void k2_gemm(const float* __restrict__ x, float* __restrict__ ws){
  __shared__ __align__(16) float As[32][36];
  __shared__ __align__(16) float Bs[32][36];
  const int i0 = blockIdx.x*32, j0 = blockIdx.y*32;
  const int t = threadIdx.x, tr = t&7, tc = t>>3;
  const float* __restrict__ U = ws + OFF_U;
  float acc[4][4] = {};
  for (int k0 = 0; k0 < DXC; k0 += 32) {
    for (int l = t; l < 1024; l += 64) {
      const int rr = l>>5, cc = l&31;
      As[cc][rr] = x[(size_t)(i0+rr)*DXC + (k0+cc)];
      Bs[cc][rr] = U[(size_t)(j0+rr)*US + (k0+cc)];
    }
    __syncthreads();
    #pragma unroll
    for (int kk=0; kk<32; kk++){
      float a[4], b[4];
      *(float4*)a = *(const float4*)&As[kk][tr*4];
      *(float4*)b = *(const float4*)&Bs[kk][tc*4];
      fma16(acc, a, b);
    }
    __syncthreads();
  }
  const float sx = ws[OFF_SCAL+2];
  float sqi[4];
  #pragma unroll
  for (int m=0;m<4;m++) sqi[m] = ws[OFF_SQX + i0+tr*4+m];
  float u6[4], u7[4];
  #pragma unroll
  for (int n=0;n<4;n++){ int j=j0+tc*4+n; u6[n]=U[(size_t)j*US+256]; u7[n]=U[(size_t)j*US+257]; }
  float* __restrict__ M1 = ws + OFF_M1;
  #pragma unroll
  for (int m=0;m<4;m++)
    #pragma unroll
    for (int n=0;n<4;n++)
      M1[(size_t)(i0+tr*4+m)*BN + (j0+tc*4+n)] = sx*(sqi[m]*u6[n] + u7[n] - 2.f*acc[m][n]);
}

// k3: Vpart[s][i][m] = sum_{j in split} M1[i,j]*zp[j,m]   (m<66)
__global__ __launch_bounds__(64) void k3_gemm(float* __restrict__ ws){
  __shared__ __align__(16) float As[32][36];
  __shared__ __align__(16) float Bs[32][36];
  const int i0 = blockIdx.x*32, m0 = blockIdx.y*32;
  const int p0 = blockIdx.z*(BN/NSPK3);
  const int t = threadIdx.x, tr = t&7, tc = t>>3;
  const float* __restrict__ M1 = ws + OFF_M1;
  const float* __restrict__ zp = ws + OFF_ZP;
  float acc[4][4] = {};
  for (int pc=0; pc<BN/NSPK3; pc+=32){
    const int pb = p0+pc;
    for (int l=t;l<1024;l+=64){
      const int rr=l>>5, cc=l&31;
      As[cc][rr] = M1[(size_t)(i0+rr)*BN + (pb+cc)];
      Bs[rr][cc] = (m0+cc < 66) ? zp[(size_t)(pb+rr)*VS + (m0+cc)] : 0.f;
    }
    __syncthreads();
    #pragma unroll
    for (int kk=0;kk<32;kk++){
      float a[4], b[4];
      *(float4*)a = *(const float4*)&As[kk][tr*4];
      *(float4*)b = *(const float4*)&Bs[kk][tc*4];
      fma16(acc, a, b);
    }
    __syncthreads();
  }
  float* __restrict__ Vp = ws + OFF_VP + (size_t)blockIdx.z*BN*VS;
  #pragma unroll
  for (int n=0;n<4;n++){
    const int m = m0 + tc*4 + n;
    if (m < 66)
      #pragma unroll
      for (int mm=0;mm<4;mm++)
        Vp[(size_t)(i0+tr*4+mm)*VS + m] = acc[mm][n];
  }
}

// also zeroes the per-row expo max accumulator for the upcoming k4/k5
__global__ __launch_bounds__(256) void k3_reduce(float* __restrict__ ws){
  int idx = blockIdx.x*256 + threadIdx.x;     // over BN*VS
  if (idx < BN) ((unsigned*)(ws + OFF_RMX))[idx] = 0u;   // enc(-inf)-ish identity
  int m = idx % VS;
  if (m >= 66) return;
  float s = 0.f;
  #pragma unroll
  for (int sp=0; sp<NSPK3; sp++) s += ws[OFF_VP + (size_t)sp*BN*VS + idx];
  ws[OFF_V + idx] = s;
}

// k4: cross[i,j] = sz*(V[i,65] + V[i,64]*sqz_j - 2*sum_m V[i,m]*z[j,m])
// final==0: K[i,j] = expo = 2*cross - constx_i - constz_j (RAW, exp applied in k5),
//           and row-max of expo accumulated into RMX (sortable-uint atomicMax)
// final==1: accumulate sum(cross * r_i K[i,j] c_j) into scal[6]
__global__ __launch_bounds__(64) void k4_cross(float* __restrict__ ws, int final_pass){
  __shared__ __align__(16) float As[32][36];
  __shared__ __align__(16) float Bs[32][36];
  const int i0 = blockIdx.x*32, j0 = blockIdx.y*32;
  const int t = threadIdx.x, tr = t&7, tc = t>>3;
  const float* __restrict__ V = ws + OFF_V;
  const float* __restrict__ zp = ws + OFF_ZP;
  float acc[4][4] = {};
  for (int k0=0; k0<DZC; k0+=32){
    for (int l=t;l<1024;l+=64){
      const int rr=l>>5, cc=l&31;
      As[cc][rr] = V[(size_t)(i0+rr)*VS + (k0+cc)];
      Bs[cc][rr] = zp[(size_t)(j0+rr)*VS + (k0+cc)];
    }
    __syncthreads();
    #pragma unroll
    for (int kk=0;kk<32;kk++){
      float a[4], b[4];
      *(float4*)a = *(const float4*)&As[kk][tr*4];
      *(float4*)b = *(const float4*)&Bs[kk][tc*4];
      fma16(acc, a, b);
    }
    __syncthreads();
  }
  const float sz = ws[OFF_SCAL+3];
  float cxl[4], v64[4], v65[4];
  #pragma unroll
  for (int m=0;m<4;m++){
    int i = i0+tr*4+m;
    cxl[m] = ws[OFF_CX+i];
    v64[m] = V[(size_t)i*VS + 64];
    v65[m] = V[(size_t)i*VS + 65];
  }
  float sqzj[4], czj[4];
  #pragma unroll
  for (int n=0;n<4;n++){ int j=j0+tc*4+n; sqzj[n]=ws[OFF_SQZ+j]; czj[n]=ws[OFF_CZ+j]; }
  float* __restrict__ Kp = ws + OFF_K;
  if (!final_pass) {
    unsigned* __restrict__ rmx = (unsigned*)(ws + OFF_RMX);
    float mxr[4];
    #pragma unroll
    for (int m=0;m<4;m++){
      mxr[m] = -3.4e38f;
      #pragma unroll
      for (int n=0;n<4;n++){
        float cross = sz*(v65[m] + v64[m]*sqzj[n] - 2.f*acc[m][n]);
        float expo = 2.f*cross - cxl[m] - czj[n];
        Kp[(size_t)(i0+tr*4+m)*BN + (j0+tc*4+n)] = expo;
        mxr[m] = fmaxf(mxr[m], expo);
      }
    }
    #pragma unroll
    for (int m=0;m<4;m++){
      float v = mxr[m];
      v = fmaxf(v, __shfl_down(v,32));
      v = fmaxf(v, __shfl_down(v,16));
      v = fmaxf(v, __shfl_down(v,8));
      if (tc==0) atomicMax(&rmx[i0+tr*4+m], encf(v));
    }
  } else {
    float rl[4], cl[4];
    #pragma unroll
    for (int m=0;m<4;m++) rl[m] = ws[OFF_R + i0+tr*4+m];
    #pragma unroll
    for (int n=0;n<4;n++) cl[n] = ws[OFF_C + j0+tc*4+n];
    float s = 0.f;
    #pragma unroll
    for (int m=0;m<4;m++)
      #pragma unroll
      for (int n=0;n<4;n++){
        float cross = sz*(v65[m] + v64[m]*sqzj[n] - 2.f*acc[m][n]);
        float tij = rl[m]*Kp[(size_t)(i0+tr*4+m)*BN + (j0+tc*4+n)]*cl[n];
        s += cross*tij;
      }
    s = wave_sum(s);
    if (t==0) atomicAdd(&ws[OFF_SCAL+6], s);
  }
}

// exp(expo - rowmax) in place + row-normalize #1: r_i = inv_b/(rowsum+1e-8)
__global__ __launch_bounds__(256) void k5_rownorm(float* __restrict__ ws){
  const int row = blockIdx.x, t = threadIdx.x;
  float* __restrict__ Kr = ws + OFF_K + (size_t)row*BN;
  const float M = decf(((const unsigned*)(ws + OFF_RMX))[row]);
  float s = 0.f;
  for (int j=t; j<BN; j+=256){
    float e = __expf(Kr[j] - M);
    Kr[j] = e;
    s += e;
  }
  __shared__ float red[256];
  red[t]=s; __syncthreads();
  for (int o=128;o;o>>=1){ if(t<o) red[t]+=red[t+o]; __syncthreads(); }
  if (t==0) ws[OFF_R+row] = INV_B/(red[0]+1e-8f);
}

// w_part[s][j] = sum_{i in split} K[i,j]*r_i ; if last also sqx-weighted
__global__ __launch_bounds__(256) void k_colpart(float* __restrict__ ws, int last){
  const int j = blockIdx.x*256 + threadIdx.x;
  const int sp = blockIdx.y;
  const int i0 = sp*(BN/NSPC);
  const float* __restrict__ Kp = ws + OFF_K;
  const float* __restrict__ rv = ws + OFF_R;
  const float* __restrict__ sqx = ws + OFF_SQX;
  float w = 0.f, w2 = 0.f;
  for (int i=i0; i<i0+BN/NSPC; i++){
    float kv = Kp[(size_t)i*BN + j];
    float ri = rv[i];
    w += kv*ri;
    if (last) w2 += kv*ri*sqx[i];
  }
  ws[OFF_CP1 + (size_t)sp*BN + j] = w;
  if (last) ws[OFF_CP2 + (size_t)sp*BN + j] = w2;
}

__global__ __launch_bounds__(256) void k_colupd(float* __restrict__ ws, int first, int last){
  const int j = blockIdx.x*256 + threadIdx.x;
  float w = 0.f;
  for (int sp=0; sp<NSPC; sp++) w += ws[OFF_CP1 + (size_t)sp*BN + j];
  float cj = ws[OFF_C+j];
  float cn = first ? (INV_B/(w + 1e-8f)) : (cj*INV_B/(cj*w + 1e-8f));
  ws[OFF_C+j] = cn;
  if (last){
    float w2 = 0.f;
    for (int sp=0; sp<NSPC; sp++) w2 += ws[OFF_CP2 + (size_t)sp*BN + j];
    ws[OFF_U + (size_t)j*US + 256] = cn*w;    // sum_i T[i,j]
    ws[OFF_U + (size_t)j*US + 257] = cn*w2;   // sum_i sqx_i T[i,j]
  }
}

__global__ __launch_bounds__(256) void k_rowstep(float* __restrict__ ws){
  const int row = blockIdx.x, t = threadIdx.x;
  const float* __restrict__ Kp = ws + OFF_K + (size_t)row*BN;
  const float* __restrict__ cv = ws + OFF_C;
  float s = 0.f;
  for (int j=t; j<BN; j+=256) s += Kp[j]*cv[j];
  __shared__ float red[256];
  red[t]=s; __syncthreads();
  for (int o=128;o;o>>=1){ if(t<o) red[t]+=red[t+o]; __syncthreads(); }
  if (t==0){
    float ri = ws[OFF_R+row];
    ws[OFF_R+row] = ri*INV_B/(ri*red[0] + 1e-8f);
  }
}

// ---------------- reg loss + finalize ----------------

__global__ __launch_bounds__(64) void k_reg(const float* __restrict__ z, const float* __restrict__ y,
                                            float* __restrict__ ws){
  __shared__ __align__(16) float As[32][36];
  __shared__ __align__(16) float Bs[32][36];
  const int i0 = blockIdx.x*32, j0 = blockIdx.y*32;
  const int t = threadIdx.x, tr = t&7, tc = t>>3;
  float acc[4][4] = {};
  for (int k0=0; k0<DZC; k0+=32){
    for (int l=t;l<1024;l+=64){
      const int rr=l>>5, cc=l&31;
      As[cc][rr] = z[(size_t)(i0+rr)*DZC + (k0+cc)];
      Bs[cc][rr] = z[(size_t)(j0+rr)*DZC + (k0+cc)];
    }
    __syncthreads();
    #pragma unroll
    for (int kk=0;kk<32;kk++){
      float a[4], b[4];
      *(float4*)a = *(const float4*)&As[kk][tr*4];
      *(float4*)b = *(const float4*)&Bs[kk][tc*4];
      fma16(acc, a, b);
    }
    __syncthreads();
  }
  const float sz = ws[OFF_SCAL+3];
  float sqi[4], yi[4];
  #pragma unroll
  for (int m=0;m<4;m++){ int i=i0+tr*4+m; sqi[m]=ws[OFF_SQZ+i]; yi[m]=y[i]; }
  float sqj[4], yj[4];
  #pragma unroll
  for (int n=0;n<4;n++){ int j=j0+tc*4+n; sqj[n]=ws[OFF_SQZ+j]; yj[n]=y[j]; }
  float s = 0.f;
  #pragma unroll
  for (int m=0;m<4;m++)
    #pragma unroll
    for (int n=0;n<4;n++){
      int i = i0+tr*4+m, j = j0+tc*4+n;
      float raw = sqi[m] + sqj[n] - 2.f*acc[m][n];
      float cz = sz*fmaxf(raw, 0.f);
      float zd = fmaxf(cz, 1e-4f);          // sqrt(max(cz^2,1e-8)) since cz>=0
      float d = logf(fabsf(yi[m]-yj[n]) + 1e-6f) - logf(zd + 1e-6f);
      if (i != j) s += d*d;
    }
  s = wave_sum(s);
  if (t==0) atomicAdd(&ws[OFF_SCAL+7], s);
}

__global__ void k_finalize(float* __restrict__ ws, float* __restrict__ out){
  float gw = ws[OFF_SCAL+4]*INV_B + ws[OFF_SCAL+5]*INV_B - 2.f*ws[OFF_SCAL+6];
  gw = fmaxf(gw, 0.f);
  float reg = ws[OFF_SCAL+7] / ((float)BN*(float)(BN-1));
  out[0] = gw + reg;
}

// ---------------- host ----------------

extern "C" void kernel_launch(void* const* d_in, const int* in_sizes, int n_in,
                              void* d_out, int out_size, void* d_ws, size_t ws_size,
                              hipStream_t stream){
  (void)in_sizes; (void)n_in; (void)out_size; (void)ws_size;
  const float* x = (const float*)d_in[0];
  const float* z = (const float*)d_in[1];
  const float* y = (const float*)d_in[2];
  float* out = (float*)d_out;
  float* ws = (float*)d_ws;

  hipLaunchKernelGGL(k_zero, dim3(8), dim3(256), 0, stream, ws);
  hipLaunchKernelGGL(k_sq_x, dim3(BN), dim3(64), 0, stream, x, ws);
  hipLaunchKernelGGL(k_sq_z, dim3(BN), dim3(64), 0, stream, z, ws);
  hipLaunchKernelGGL(HIP_KERNEL_NAME(k_stats<DXC>), dim3(64,64), dim3(64), 0, stream,
                     x, ws+OFF_SQX, ws, 0, ws+OFF_RSQX);
  hipLaunchKernelGGL(HIP_KERNEL_NAME(k_stats<DZC>), dim3(64,64), dim3(64), 0, stream,
                     z, ws+OFF_SQZ, ws, 1, ws+OFF_RSQZ);
  hipLaunchKernelGGL(k_s3, dim3(8), dim3(256), 0, stream, z, ws);
  hipLaunchKernelGGL(k_initK, dim3(4096), dim3(256), 0, stream, ws);

  for (int it = 0; it < NITER; it++){
    hipLaunchKernelGGL(k1_gemm, dim3(8,64,NSPK1), dim3(64), 0, stream, x, ws);
    hipLaunchKernelGGL(k1_reduce, dim3(2048), dim3(256), 0, stream, ws);
    hipLaunchKernelGGL(k2_gemm, dim3(64,64), dim3(64), 0, stream, x, ws);
    hipLaunchKernelGGL(k3_gemm, dim3(64,3,NSPK3), dim3(64), 0, stream, ws);
    hipLaunchKernelGGL(k3_reduce, dim3(544), dim3(256), 0, stream, ws);
    hipLaunchKernelGGL(k4_cross, dim3(64,64), dim3(64), 0, stream, ws, 0);
    hipLaunchKernelGGL(k5_rownorm, dim3(BN), dim3(256), 0, stream, ws);
    for (int n = 0; n < 5; n++){
      hipLaunchKernelGGL(k_colpart, dim3(8,NSPC), dim3(256), 0, stream, ws, (n==4)?1:0);
      hipLaunchKernelGGL(k_colupd, dim3(8), dim3(256), 0, stream, ws, (n==0)?1:0, (n==4)?1:0);
      if (n < 4)
        hipLaunchKernelGGL(k_rowstep, dim3(BN), dim3(256), 0, stream, ws);
    }
  }

  // final evaluation with converged T = diag(r) K diag(c)
  hipLaunchKernelGGL(k1_gemm, dim3(8,64,NSPK1), dim3(64), 0, stream, x, ws);
  hipLaunchKernelGGL(k1_reduce, dim3(2048), dim3(256), 0, stream, ws);
  hipLaunchKernelGGL(k2_gemm, dim3(64,64), dim3(64), 0, stream, x, ws);
  hipLaunchKernelGGL(k3_gemm, dim3(64,3,NSPK3), dim3(64), 0, stream, ws);
  hipLaunchKernelGGL(k3_reduce, dim3(544), dim3(256), 0, stream, ws);
  hipLaunchKernelGGL(k4_cross, dim3(64,64), dim3(64), 0, stream, ws, 1);
  hipLaunchKernelGGL(k_reg, dim3(64,64), dim3(64), 0, stream, z, y, ws);
  hipLaunchKernelGGL(k_finalize, dim3(1), dim3(1), 0, stream, ws, out);
}

// Round 3
// 6397.417 us; speedup vs baseline: 2.4976x; 2.4976x over previous
//
#include <hip/hip_runtime.h>
#include <cmath>

#define BN 2048
#define DXC 256
#define DZC 64
#define INV_B (1.0f/2048.0f)
#define NITER 50

typedef unsigned short ushortT;
typedef __attribute__((ext_vector_type(8))) short s8;
typedef __attribute__((ext_vector_type(4))) float f4;

// ---- workspace layout (float offsets) ----
#define OFF_SH   ((size_t)0)          // 4M floats (16MB), shared by UP / VP / E
#define OFF_KB   ((size_t)4194304)    // ushort KbT[2048][2048]
#define OFF_M1B  ((size_t)6291456)    // ushort M1b[2048][2048]
#define OFF_UB   ((size_t)8388608)    // ushort Ub[2048][256]
#define OFF_XB   ((size_t)8650752)    // ushort xb[2048][256]
#define OFF_XRT  ((size_t)8912896)    // ushort xrbT[256][2048]
#define OFF_VB   ((size_t)9175040)    // ushort Vb[2048][64]
#define OFF_ZB   ((size_t)9240576)    // ushort zb[2048][64]
#define OFF_ZTB  ((size_t)9306112)    // ushort zTb[128][2048]
#define OFF_V64  ((size_t)9437184)
#define OFF_V65  ((size_t)9439232)
#define OFF_SQX  ((size_t)9441280)
#define OFF_SQZ  ((size_t)9443328)
#define OFF_CX   ((size_t)9445376)
#define OFF_CZ   ((size_t)9447424)
#define OFF_R    ((size_t)9449472)
#define OFF_C    ((size_t)9451520)
#define OFF_RSQX ((size_t)9453568)
#define OFF_RSQZ ((size_t)9455616)
#define OFF_U6   ((size_t)9457664)
#define OFF_U7   ((size_t)9459712)
#define OFF_CP1  ((size_t)9461760)    // [32][2048]
#define OFF_RMX  ((size_t)9527296)
#define OFF_SCAL ((size_t)9529344)
// scal: 0=sum Craw_x, 1=sum Craw_z, 2=sx, 3=sz, 4=sum constx, 5=sum constz,
//       6=cross_term, 7=reg_sum, 8=sum sqx

__device__ __forceinline__ float wave_sum(float v){
  for (int o=32;o;o>>=1) v += __shfl_down(v,o);
  return v;
}
__device__ __forceinline__ void fma16(float (&acc)[4][4], const float* a4, const float* b4){
  #pragma unroll
  for (int m=0;m<4;m++)
    #pragma unroll
    for (int n=0;n<4;n++)
      acc[m][n] = fmaf(a4[m], b4[n], acc[m][n]);
}
__device__ __forceinline__ unsigned encf(float f){
  unsigned u = __float_as_uint(f);
  return (u & 0x80000000u) ? ~u : (u | 0x80000000u);
}
__device__ __forceinline__ float decf(unsigned u){
  return (u & 0x80000000u) ? __uint_as_float(u & 0x7fffffffu) : __uint_as_float(~u);
}
__device__ __forceinline__ ushortT f2bf(float f){
  unsigned u = __float_as_uint(f);
  return (ushortT)((u + 0x7FFFu + ((u>>16)&1u)) >> 16);
}
__device__ __forceinline__ float bf2f(ushortT v){
  return __uint_as_float(((unsigned)v)<<16);
}
__device__ __forceinline__ void gload16(const void* g, void* l){
  __builtin_amdgcn_global_load_lds((const __attribute__((address_space(1))) void*)g,
                                   (__attribute__((address_space(3))) void*)l, 16, 0, 0);
}

// ---------------- MFMA core: C[128,128] tile, A[M][K] bf16, BT[N][K] bf16 ----
__device__ __forceinline__ void gemm_core(const ushortT* __restrict__ A, int ldA,
                                          const ushortT* __restrict__ B, int ldB,
                                          int m0, int n0, int kstart, int ksteps,
                                          ushortT* As, ushortT* Bs, f4 (&acc)[4][4]){
  const int t = threadIdx.x, w = t>>6, lane = t&63;
  const int wr = w>>1, wc = w&1;
  const int lrow = lane&15, quad = lane>>4;
  const int r0 = w*32;
  const int srow = lane>>3, schunk = (lane&7)*8;
  for (int ks = 0; ks < ksteps; ks++){
    const int kk0 = kstart + ks*64;
    __syncthreads();
    #pragma unroll
    for (int q=0;q<4;q++){
      const int row = r0 + q*8 + srow;
      gload16(A + (size_t)(m0+row)*ldA + kk0 + schunk, As + (r0 + q*8)*64);
    }
    #pragma unroll
    for (int q=0;q<4;q++){
      const int row = r0 + q*8 + srow;
      gload16(B + (size_t)(n0+row)*ldB + kk0 + schunk, Bs + (r0 + q*8)*64);
    }
    __syncthreads();
    #pragma unroll
    for (int kk=0;kk<2;kk++){
      s8 af[4], bf[4];
      #pragma unroll
      for (int tm=0;tm<4;tm++)
        af[tm] = *(const s8*)(As + (wr*64 + tm*16 + lrow)*64 + kk*32 + quad*8);
      #pragma unroll
      for (int tn=0;tn<4;tn++)
        bf[tn] = *(const s8*)(Bs + (wc*64 + tn*16 + lrow)*64 + kk*32 + quad*8);
      #pragma unroll
      for (int tm=0;tm<4;tm++)
        #pragma unroll
        for (int tn=0;tn<4;tn++)
          acc[tm][tn] = __builtin_amdgcn_mfma_f32_16x16x32_bf16(af[tm], bf[tn], acc[tm][tn], 0,0,0);
    }
  }
}

// ---------------- setup kernels ----------------

__global__ __launch_bounds__(256) void k_zero(float* __restrict__ ws){
  int t = blockIdx.x*256 + threadIdx.x;
  if (t < BN) { ws[OFF_RSQX + t] = 0.f; ws[OFF_RSQZ + t] = 0.f; }
  if (t < 64) ws[OFF_SCAL + t] = 0.f;
}

__global__ __launch_bounds__(64) void k_sq_x(const float* __restrict__ x, float* __restrict__ ws){
  int row = blockIdx.x, t = threadIdx.x;
  const float* xr = x + (size_t)row*DXC;
  float s = 0.f;
  for (int k = t; k < DXC; k += 64) { float v = xr[k]; s += v*v; }
  s = wave_sum(s);
  if (t == 0) { ws[OFF_SQX + row] = s; atomicAdd(&ws[OFF_SCAL+8], s); }
}

__global__ __launch_bounds__(64) void k_sq_z(const float* __restrict__ z, float* __restrict__ ws){
  int row = blockIdx.x, t = threadIdx.x;
  float v = (t < DZC) ? z[(size_t)row*DZC + t] : 0.f;
  float s = wave_sum(v*v);
  if (t == 0) ws[OFF_SQZ + row] = s;
}

template<int D>
__global__ __launch_bounds__(64) void k_stats(const float* __restrict__ P,
                                              const float* __restrict__ sq,
                                              float* __restrict__ ws, int sumidx,
                                              float* __restrict__ rowsq){
  __shared__ __align__(16) float As[32][36];
  __shared__ __align__(16) float Bs[32][36];
  const int i0 = blockIdx.x*32, j0 = blockIdx.y*32;
  const int t = threadIdx.x, tr = t&7, tc = t>>3;
  float acc[4][4] = {};
  for (int k0 = 0; k0 < D; k0 += 32) {
    for (int l = t; l < 1024; l += 64) {
      const int rr = l>>5, cc = l&31;
      As[cc][rr] = P[(size_t)(i0+rr)*D + (k0+cc)];
      Bs[cc][rr] = P[(size_t)(j0+rr)*D + (k0+cc)];
    }
    __syncthreads();
    #pragma unroll
    for (int kk = 0; kk < 32; kk++) {
      float a[4], b[4];
      *(float4*)a = *(const float4*)&As[kk][tr*4];
      *(float4*)b = *(const float4*)&Bs[kk][tc*4];
      fma16(acc, a, b);
    }
    __syncthreads();
  }
  float sqi[4], sqj[4];
  #pragma unroll
  for (int m=0;m<4;m++) sqi[m] = sq[i0+tr*4+m];
  #pragma unroll
  for (int n=0;n<4;n++) sqj[n] = sq[j0+tc*4+n];
  float tot = 0.f; float rs[4] = {0.f,0.f,0.f,0.f};
  #pragma unroll
  for (int m=0;m<4;m++)
    #pragma unroll
    for (int n=0;n<4;n++) {
      float raw = sqi[m] + sqj[n] - 2.f*acc[m][n];
      float cr = fmaxf(raw, 0.f);
      tot += cr;
      rs[m] += cr*cr;
    }
  float v = wave_sum(tot);
  if (t==0) atomicAdd(&ws[OFF_SCAL+sumidx], v);
  #pragma unroll
  for (int m=0;m<4;m++){
    float x2 = rs[m];
    x2 += __shfl_down(x2,32); x2 += __shfl_down(x2,16); x2 += __shfl_down(x2,8);
    if (tc==0) atomicAdd(&rowsq[i0+tr*4+m], x2);
  }
}

// scalars, per-row consts, r/c init, static bf16 z copies
__global__ __launch_bounds__(256) void k_s3(const float* __restrict__ z, float* __restrict__ ws){
  int j = blockIdx.x*256 + threadIdx.x;
  float mx = ws[OFF_SCAL+0] / ((float)BN*(float)BN);
  float sx = 1.f/(mx + 1e-8f);
  float mz = ws[OFF_SCAL+1] / ((float)BN*(float)BN);
  float sz = 1.f/(mz + 1e-8f);
  if (j == 0) { ws[OFF_SCAL+2] = sx; ws[OFF_SCAL+3] = sz; }
  if (j < BN) {
    float cx = ws[OFF_RSQX+j]*sx*sx*INV_B;
    float cz = ws[OFF_RSQZ+j]*sz*sz*INV_B;
    ws[OFF_CX+j] = cx; ws[OFF_CZ+j] = cz;
    atomicAdd(&ws[OFF_SCAL+4], cx);
    atomicAdd(&ws[OFF_SCAL+5], cz);
    ws[OFF_R+j] = INV_B; ws[OFF_C+j] = 1.f;
    float msx = ws[OFF_SCAL+8]*INV_B;
    ws[OFF_U6+j] = 1.f;      // sum_i T0[i,j]
    ws[OFF_U7+j] = msx;      // sum_i sqx_i T0[i,j]
    ushortT* zb  = (ushortT*)(ws + OFF_ZB);
    ushortT* zTb = (ushortT*)(ws + OFF_ZTB);
    for (int m=0;m<DZC;m++){
      ushortT v = f2bf(z[(size_t)j*DZC + m]);
      zb[(size_t)j*DZC + m] = v;
      zTb[(size_t)m*BN + j] = v;
    }
    zTb[(size_t)64*BN + j] = 0x3F80;               // 1.0
    zTb[(size_t)65*BN + j] = f2bf(ws[OFF_SQZ+j]);  // sqz
    for (int m=66;m<128;m++) zTb[(size_t)m*BN + j] = 0;
  }
}

__global__ __launch_bounds__(256) void k_cvt_x(const float* __restrict__ x, float* __restrict__ ws){
  int idx = blockIdx.x*256 + threadIdx.x;          // over 2048*256
  ((ushortT*)(ws + OFF_XB))[idx] = f2bf(x[idx]);
}

__global__ __launch_bounds__(256) void k_fillKb(float* __restrict__ ws){
  size_t idx = (size_t)blockIdx.x*256 + threadIdx.x;   // 524288 x 16B
  uint4 v = {0x3F803F80u, 0x3F803F80u, 0x3F803F80u, 0x3F803F80u};
  ((uint4*)(ws + OFF_KB))[idx] = v;
}

// ---------------- per-iteration kernels ----------------

// xrbT[k][i] = bf16(r_i * x[i,k])  (tiled transpose)
__global__ __launch_bounds__(256) void k_prepx(const float* __restrict__ x, float* __restrict__ ws){
  __shared__ float tr[64*65];
  const int i0 = blockIdx.x*64, k0 = blockIdx.y*64;
  const int t = threadIdx.x;
  const float* __restrict__ R = ws + OFF_R;
  #pragma unroll
  for (int s=0;s<16;s++){
    int il = (t>>6) + s*4;
    tr[(t&63)*65 + il] = x[(size_t)(i0+il)*DXC + k0 + (t&63)] * R[i0+il];
  }
  __syncthreads();
  ushortT* __restrict__ XRT = (ushortT*)(ws + OFF_XRT);
  #pragma unroll
  for (int s=0;s<16;s++){
    int kl = (t>>6) + s*4;
    XRT[(size_t)(k0+kl)*BN + i0 + (t&63)] = f2bf(tr[kl*65 + (t&63)]);
  }
}

// k1: UP[sp][j][k] = sum_{i in split} KbT[j,i]*xrbT[k,i]
__global__ __launch_bounds__(256) void k1_mfma(float* __restrict__ ws){
  __shared__ __align__(16) ushortT As[128*64];
  __shared__ __align__(16) ushortT Bs[128*64];
  const int m0 = blockIdx.x*128, n0 = blockIdx.y*128, sp = blockIdx.z;
  f4 acc[4][4] = {};
  gemm_core((const ushortT*)(ws+OFF_KB), BN, (const ushortT*)(ws+OFF_XRT), BN,
            m0, n0, sp*256, 4, As, Bs, acc);
  float* __restrict__ UP = ws + OFF_SH + (size_t)sp*BN*DXC;
  const int t = threadIdx.x, w = t>>6, lane = t&63;
  const int wr = w>>1, wc = w&1, lrow = lane&15, quad = lane>>4;
  #pragma unroll
  for (int tm=0;tm<4;tm++)
    #pragma unroll
    for (int tn=0;tn<4;tn++)
      #pragma unroll
      for (int rg=0;rg<4;rg++)
        UP[(size_t)(m0+wr*64+tm*16+quad*4+rg)*DXC + n0+wc*64+tn*16+lrow] = acc[tm][tn][rg];
}

// Ub[j][k] = bf16(c_j * sum_sp UP)
__global__ __launch_bounds__(256) void k1_red(float* __restrict__ ws){
  int idx = blockIdx.x*256 + threadIdx.x;   // over 2048*256
  int j = idx >> 8;
  float s = 0.f;
  #pragma unroll
  for (int sp=0;sp<8;sp++) s += ws[OFF_SH + (size_t)sp*BN*DXC + idx];
  ((ushortT*)(ws + OFF_UB))[idx] = f2bf(s * ws[OFF_C + j]);
}

// k2: M1b[i][j] = bf16( sx*(sqx_i*u6_j + u7_j - 2*sum_k xb[i,k]*Ub[j,k]) )
__global__ __launch_bounds__(256) void k2_mfma(float* __restrict__ ws){
  __shared__ __align__(16) ushortT As[128*64];
  __shared__ __align__(16) ushortT Bs[128*64];
  const int m0 = blockIdx.x*128, n0 = blockIdx.y*128;
  f4 acc[4][4] = {};
  gemm_core((const ushortT*)(ws+OFF_XB), DXC, (const ushortT*)(ws+OFF_UB), DXC,
            m0, n0, 0, 4, As, Bs, acc);
  const float sx = ws[OFF_SCAL+2];
  const int t = threadIdx.x, w = t>>6, lane = t&63;
  const int wr = w>>1, wc = w&1, lrow = lane&15, quad = lane>>4;
  ushortT* __restrict__ M1 = (ushortT*)(ws + OFF_M1B);
  #pragma unroll
  for (int tn=0;tn<4;tn++){
    const int j = n0 + wc*64 + tn*16 + lrow;
    const float u6 = ws[OFF_U6+j], u7 = ws[OFF_U7+j];
    #pragma unroll
    for (int tm=0;tm<4;tm++)
      #pragma unroll
      for (int rg=0;rg<4;rg++){
        const int i = m0 + wr*64 + tm*16 + quad*4 + rg;
        M1[(size_t)i*BN + j] = f2bf(sx*(ws[OFF_SQX+i]*u6 + u7 - 2.f*acc[tm][tn][rg]));
      }
  }
}

// k3: VP[sp][i][m] = sum_{j in split} M1b[i,j]*zTb[m,j]
__global__ __launch_bounds__(256) void k3_mfma(float* __restrict__ ws){
  __shared__ __align__(16) ushortT As[128*64];
  __shared__ __align__(16) ushortT Bs[128*64];
  const int m0 = blockIdx.x*128, sp = blockIdx.z;
  f4 acc[4][4] = {};
  gemm_core((const ushortT*)(ws+OFF_M1B), BN, (const ushortT*)(ws+OFF_ZTB), BN,
            m0, 0, sp*128, 2, As, Bs, acc);
  float* __restrict__ VP = ws + OFF_SH + (size_t)sp*BN*128;
  const int t = threadIdx.x, w = t>>6, lane = t&63;
  const int wr = w>>1, wc = w&1, lrow = lane&15, quad = lane>>4;
  #pragma unroll
  for (int tm=0;tm<4;tm++)
    #pragma unroll
    for (int tn=0;tn<4;tn++)
      #pragma unroll
      for (int rg=0;rg<4;rg++)
        VP[(size_t)(m0+wr*64+tm*16+quad*4+rg)*128 + wc*64+tn*16+lrow] = acc[tm][tn][rg];
}

// reduce V partials; split m<64 -> Vb bf16, m=64/65 -> f32; zero RMX
__global__ __launch_bounds__(256) void k3_red(float* __restrict__ ws){
  int idx = blockIdx.x*256 + threadIdx.x;   // over 2048*128
  if (idx < BN) ((unsigned*)(ws + OFF_RMX))[idx] = 0u;
  int i = idx >> 7, m = idx & 127;
  if (m >= 66) return;
  float s = 0.f;
  #pragma unroll
  for (int sp=0;sp<16;sp++) s += ws[OFF_SH + (size_t)sp*BN*128 + idx];
  if (m < 64)      ((ushortT*)(ws + OFF_VB))[(size_t)i*64 + m] = f2bf(s);
  else if (m == 64) ws[OFF_V64 + i] = s;
  else              ws[OFF_V65 + i] = s;
}

// k4: acc = sum_m zb[j,m]*Vb[i,m]; expo[j,i] (transposed E!) or final cross_term
__global__ __launch_bounds__(256) void k4_mfma(float* __restrict__ ws, int final_pass){
  __shared__ __align__(16) ushortT As[128*64];
  __shared__ __align__(16) ushortT Bs[128*64];
  const int m0 = blockIdx.x*128, n0 = blockIdx.y*128;   // m=j rows, n=i cols
  f4 acc[4][4] = {};
  gemm_core((const ushortT*)(ws+OFF_ZB), DZC, (const ushortT*)(ws+OFF_VB), DZC,
            m0, n0, 0, 1, As, Bs, acc);
  const float sz = ws[OFF_SCAL+3];
  const int t = threadIdx.x, w = t>>6, lane = t&63;
  const int wr = w>>1, wc = w&1, lrow = lane&15, quad = lane>>4;
  if (!final_pass){
    float* __restrict__ E = ws + OFF_SH;
    unsigned* __restrict__ rmx = (unsigned*)(ws + OFF_RMX);
    #pragma unroll
    for (int tn=0;tn<4;tn++){
      const int i = n0 + wc*64 + tn*16 + lrow;
      const float v64 = ws[OFF_V64+i], v65 = ws[OFF_V65+i], cx = ws[OFF_CX+i];
      float mx = -3.4e38f;
      #pragma unroll
      for (int tm=0;tm<4;tm++)
        #pragma unroll
        for (int rg=0;rg<4;rg++){
          const int j = m0 + wr*64 + tm*16 + quad*4 + rg;
          float cross = sz*(v65 + v64*ws[OFF_SQZ+j] - 2.f*acc[tm][tn][rg]);
          float expo = 2.f*cross - cx - ws[OFF_CZ+j];
          E[(size_t)j*BN + i] = expo;
          mx = fmaxf(mx, expo);
        }
      mx = fmaxf(mx, __shfl_down(mx,32));
      mx = fmaxf(mx, __shfl_down(mx,16));
      if (quad == 0) atomicMax(&rmx[i], encf(mx));
    }
  } else {
    const ushortT* __restrict__ Kb = (const ushortT*)(ws + OFF_KB);
    float s = 0.f;
    #pragma unroll
    for (int tn=0;tn<4;tn++){
      const int i = n0 + wc*64 + tn*16 + lrow;
      const float v64 = ws[OFF_V64+i], v65 = ws[OFF_V65+i], ri = ws[OFF_R+i];
      #pragma unroll
      for (int tm=0;tm<4;tm++)
        #pragma unroll
        for (int rg=0;rg<4;rg++){
          const int j = m0 + wr*64 + tm*16 + quad*4 + rg;
          float cross = sz*(v65 + v64*ws[OFF_SQZ+j] - 2.f*acc[tm][tn][rg]);
          float tij = ri * bf2f(Kb[(size_t)j*BN + i]) * ws[OFF_C+j];
          s += cross*tij;
        }
    }
    s = wave_sum(s);
    if (lane == 0) atomicAdd(&ws[OFF_SCAL+6], s);
  }
}

// k5a: Kb[j][i] = bf16(exp(E[j][i]-M_i)); col partial sums (over j) -> CP1
__global__ __launch_bounds__(256) void k5a_exp(float* __restrict__ ws){
  const int i = blockIdx.x*256 + threadIdx.x;
  const int sp = blockIdx.y;
  const float Mi = decf(((const unsigned*)(ws + OFF_RMX))[i]);
  const float* __restrict__ E = ws + OFF_SH;
  ushortT* __restrict__ Kb = (ushortT*)(ws + OFF_KB);
  float s = 0.f;
  for (int jj=0; jj<64; jj++){
    int j = sp*64 + jj;
    float e = __expf(E[(size_t)j*BN + i] - Mi);
    ushortT v = f2bf(e);
    Kb[(size_t)j*BN + i] = v;
    s += bf2f(v);
  }
  ws[OFF_CP1 + (size_t)sp*BN + i] = s;
}

__global__ __launch_bounds__(256) void k5b_r(float* __restrict__ ws){
  const int i = blockIdx.x*256 + threadIdx.x;
  float s = 0.f;
  #pragma unroll
  for (int sp=0;sp<32;sp++) s += ws[OFF_CP1 + (size_t)sp*BN + i];
  ws[OFF_R+i] = INV_B/(s + 1e-8f);
}

// c-update: s1 = sum_i Kb[j,i]*r_i (+ s2 with sqx); block per row j
__global__ __launch_bounds__(256) void k_c(float* __restrict__ ws, int first, int last){
  __shared__ float red1[256];
  __shared__ float red2[256];
  const int j = blockIdx.x, t = threadIdx.x;
  const ushortT* __restrict__ Kr = (const ushortT*)(ws + OFF_KB) + (size_t)j*BN;
  const float* __restrict__ R = ws + OFF_R;
  const float* __restrict__ SQ = ws + OFF_SQX;
  float s1 = 0.f, s2 = 0.f;
  #pragma unroll
  for (int q=0;q<8;q++){
    int i = t + q*256;
    float kv = bf2f(Kr[i]) * R[i];
    s1 += kv;
    if (last) s2 += kv*SQ[i];
  }
  red1[t] = s1; red2[t] = s2; __syncthreads();
  for (int o=128;o;o>>=1){ if(t<o){ red1[t]+=red1[t+o]; red2[t]+=red2[t+o]; } __syncthreads(); }
  if (t==0){
    float s = red1[0];
    float cj = ws[OFF_C+j];
    float cn = first ? (INV_B/(s + 1e-8f)) : (cj*INV_B/(cj*s + 1e-8f));
    ws[OFF_C+j] = cn;
    if (last){
      ws[OFF_U6+j] = cn*s;
      ws[OFF_U7+j] = cn*red2[0];
    }
  }
}

// r-update part: CP1[sp][i] = sum_{j in split} Kb[j,i]*c_j
__global__ __launch_bounds__(256) void k_ra(float* __restrict__ ws){
  const int i = blockIdx.x*256 + threadIdx.x;
  const int sp = blockIdx.y;
  const ushortT* __restrict__ Kb = (const ushortT*)(ws + OFF_KB);
  const float* __restrict__ C = ws + OFF_C;
  float s = 0.f;
  for (int jj=0;jj<64;jj++){
    int j = sp*64 + jj;
    s += bf2f(Kb[(size_t)j*BN + i]) * C[j];
  }
  ws[OFF_CP1 + (size_t)sp*BN + i] = s;
}

__global__ __launch_bounds__(256) void k_rb(float* __restrict__ ws){
  const int i = blockIdx.x*256 + threadIdx.x;
  float s = 0.f;
  #pragma unroll
  for (int sp=0;sp<32;sp++) s += ws[OFF_CP1 + (size_t)sp*BN + i];
  float ri = ws[OFF_R+i];
  ws[OFF_R+i] = ri*INV_B/(ri*s + 1e-8f);
}

// ---------------- reg loss + finalize ----------------

__global__ __launch_bounds__(64) void k_reg(const float* __restrict__ z, const float* __restrict__ y,
                                            float* __restrict__ ws){
  __shared__ __align__(16) float As[32][36];
  __shared__ __align__(16) float Bs[32][36];
  const int i0 = blockIdx.x*32, j0 = blockIdx.y*32;
  const int t = threadIdx.x, tr = t&7, tc = t>>3;
  float acc[4][4] = {};
  for (int k0=0; k0<DZC; k0+=32){
    for (int l=t;l<1024;l+=64){
      const int rr=l>>5, cc=l&31;
      As[cc][rr] = z[(size_t)(i0+rr)*DZC + (k0+cc)];
      Bs[cc][rr] = z[(size_t)(j0+rr)*DZC + (k0+cc)];
    }
    __syncthreads();
    #pragma unroll
    for (int kk=0;kk<32;kk++){
      float a[4], b[4];
      *(float4*)a = *(const float4*)&As[kk][tr*4];
      *(float4*)b = *(const float4*)&Bs[kk][tc*4];
      fma16(acc, a, b);
    }
    __syncthreads();
  }
  const float sz = ws[OFF_SCAL+3];
  float sqi[4], yi[4];
  #pragma unroll
  for (int m=0;m<4;m++){ int i=i0+tr*4+m; sqi[m]=ws[OFF_SQZ+i]; yi[m]=y[i]; }
  float sqj[4], yj[4];
  #pragma unroll
  for (int n=0;n<4;n++){ int j=j0+tc*4+n; sqj[n]=ws[OFF_SQZ+j]; yj[n]=y[j]; }
  float s = 0.f;
  #pragma unroll
  for (int m=0;m<4;m++)
    #pragma unroll
    for (int n=0;n<4;n++){
      int i = i0+tr*4+m, j = j0+tc*4+n;
      float raw = sqi[m] + sqj[n] - 2.f*acc[m][n];
      float cz = sz*fmaxf(raw, 0.f);
      float zd = fmaxf(cz, 1e-4f);
      float d = logf(fabsf(yi[m]-yj[n]) + 1e-6f) - logf(zd + 1e-6f);
      if (i != j) s += d*d;
    }
  s = wave_sum(s);
  if (t==0) atomicAdd(&ws[OFF_SCAL+7], s);
}

__global__ void k_finalize(float* __restrict__ ws, float* __restrict__ out){
  float gw = ws[OFF_SCAL+4]*INV_B + ws[OFF_SCAL+5]*INV_B - 2.f*ws[OFF_SCAL+6];
  gw = fmaxf(gw, 0.f);
  float reg = ws[OFF_SCAL+7] / ((float)BN*(float)(BN-1));
  out[0] = gw + reg;
}

// ---------------- host ----------------

extern "C" void kernel_launch(void* const* d_in, const int* in_sizes, int n_in,
                              void* d_out, int out_size, void* d_ws, size_t ws_size,
                              hipStream_t stream){
  (void)in_sizes; (void)n_in; (void)out_size; (void)ws_size;
  const float* x = (const float*)d_in[0];
  const float* z = (const float*)d_in[1];
  const float* y = (const float*)d_in[2];
  float* out = (float*)d_out;
  float* ws = (float*)d_ws;

  hipLaunchKernelGGL(k_zero, dim3(8), dim3(256), 0, stream, ws);
  hipLaunchKernelGGL(k_sq_x, dim3(BN), dim3(64), 0, stream, x, ws);
  hipLaunchKernelGGL(k_sq_z, dim3(BN), dim3(64), 0, stream, z, ws);
  hipLaunchKernelGGL(HIP_KERNEL_NAME(k_stats<DXC>), dim3(64,64), dim3(64), 0, stream,
                     x, ws+OFF_SQX, ws, 0, ws+OFF_RSQX);
  hipLaunchKernelGGL(HIP_KERNEL_NAME(k_stats<DZC>), dim3(64,64), dim3(64), 0, stream,
                     z, ws+OFF_SQZ, ws, 1, ws+OFF_RSQZ);
  hipLaunchKernelGGL(k_s3, dim3(8), dim3(256), 0, stream, z, ws);
  hipLaunchKernelGGL(k_cvt_x, dim3(2048), dim3(256), 0, stream, x, ws);
  hipLaunchKernelGGL(k_fillKb, dim3(2048), dim3(256), 0, stream, ws);

  for (int it = 0; it < NITER; it++){
    hipLaunchKernelGGL(k_prepx, dim3(32,4), dim3(256), 0, stream, x, ws);
    hipLaunchKernelGGL(k1_mfma, dim3(16,2,8), dim3(256), 0, stream, ws);
    hipLaunchKernelGGL(k1_red, dim3(2048), dim3(256), 0, stream, ws);
    hipLaunchKernelGGL(k2_mfma, dim3(16,16), dim3(256), 0, stream, ws);
    hipLaunchKernelGGL(k3_mfma, dim3(16,1,16), dim3(256), 0, stream, ws);
    hipLaunchKernelGGL(k3_red, dim3(1024), dim3(256), 0, stream, ws);
    hipLaunchKernelGGL(k4_mfma, dim3(16,16), dim3(256), 0, stream, ws, 0);
    hipLaunchKernelGGL(k5a_exp, dim3(8,32), dim3(256), 0, stream, ws);
    hipLaunchKernelGGL(k5b_r, dim3(8), dim3(256), 0, stream, ws);
    for (int n = 0; n < 5; n++){
      hipLaunchKernelGGL(k_c, dim3(BN), dim3(256), 0, stream, ws, (n==0)?1:0, (n==4)?1:0);
      if (n < 4){
        hipLaunchKernelGGL(k_ra, dim3(8,32), dim3(256), 0, stream, ws);
        hipLaunchKernelGGL(k_rb, dim3(8), dim3(256), 0, stream, ws);
      }
    }
  }

  // final evaluation with converged T = diag(r) Kb diag(c)
  hipLaunchKernelGGL(k_prepx, dim3(32,4), dim3(256), 0, stream, x, ws);
  hipLaunchKernelGGL(k1_mfma, dim3(16,2,8), dim3(256), 0, stream, ws);
  hipLaunchKernelGGL(k1_red, dim3(2048), dim3(256), 0, stream, ws);
  hipLaunchKernelGGL(k2_mfma, dim3(16,16), dim3(256), 0, stream, ws);
  hipLaunchKernelGGL(k3_mfma, dim3(16,1,16), dim3(256), 0, stream, ws);
  hipLaunchKernelGGL(k3_red, dim3(1024), dim3(256), 0, stream, ws);
  hipLaunchKernelGGL(k4_mfma, dim3(16,16), dim3(256), 0, stream, ws, 1);
  hipLaunchKernelGGL(k_reg, dim3(64,64), dim3(64), 0, stream, z, y, ws);
  hipLaunchKernelGGL(k_finalize, dim3(1), dim3(1), 0, stream, ws, out);
}